// Round 1
// baseline (741.246 us; speedup 1.0000x reference)
//
#include <hip/hip_runtime.h>

#define HASH_SIZE 256
#define OFFSET_SIZE 64
#define FEAT 8

// One thread per query.
//   oidx = int(float(c) * m1) & 63       -> gather int3 from offset_table (3 MB, cache-resident)
//   hidx = (int(float(c) * m0) + off) & 255 -> gather float8 (32B aligned) from hash_table (512 MB)
// All intermediate values are non-negative, so % pow2 == & (pow2-1), matching Python semantics.
__global__ void __launch_bounds__(256)
psh_kernel(const int* __restrict__ coords,
           const float* __restrict__ hash_table,
           const int* __restrict__ offset_table,
           const float* __restrict__ m0,
           const float* __restrict__ m1,
           float* __restrict__ out,
           int n) {
    int i = blockIdx.x * blockDim.x + threadIdx.x;
    if (i >= n) return;

    // m0/m1 are wave-uniform; compiler hoists these to scalar loads.
    float m0x = m0[0], m0y = m0[1], m0z = m0[2];
    float m1x = m1[0], m1y = m1[1], m1z = m1[2];

    int cx = coords[3 * i + 0];
    int cy = coords[3 * i + 1];
    int cz = coords[3 * i + 2];

    int ox = ((int)((float)cx * m1x)) & (OFFSET_SIZE - 1);
    int oy = ((int)((float)cy * m1y)) & (OFFSET_SIZE - 1);
    int oz = ((int)((float)cz * m1z)) & (OFFSET_SIZE - 1);

    size_t ooff = ((size_t)((ox * OFFSET_SIZE + oy) * OFFSET_SIZE + oz)) * 3;
    int dx = offset_table[ooff + 0];
    int dy = offset_table[ooff + 1];
    int dz = offset_table[ooff + 2];

    int hx = (((int)((float)cx * m0x)) + dx) & (HASH_SIZE - 1);
    int hy = (((int)((float)cy * m0y)) + dy) & (HASH_SIZE - 1);
    int hz = (((int)((float)cz * m0z)) + dz) & (HASH_SIZE - 1);

    size_t hoff = (((size_t)hx * HASH_SIZE + hy) * HASH_SIZE + hz) * FEAT;
    const float4* hp = (const float4*)(hash_table + hoff);
    float4 f0 = hp[0];
    float4 f1 = hp[1];

    float4* op = (float4*)(out + (size_t)i * FEAT);
    op[0] = f0;
    op[1] = f1;
}

extern "C" void kernel_launch(void* const* d_in, const int* in_sizes, int n_in,
                              void* d_out, int out_size, void* d_ws, size_t ws_size,
                              hipStream_t stream) {
    const int*   coords       = (const int*)d_in[0];
    const float* hash_table   = (const float*)d_in[1];
    const int*   offset_table = (const int*)d_in[2];
    const float* m0           = (const float*)d_in[3];
    const float* m1           = (const float*)d_in[4];
    float*       out          = (float*)d_out;

    int n = in_sizes[0] / 3;  // 4,000,000 queries
    int block = 256;
    int grid = (n + block - 1) / block;
    psh_kernel<<<grid, block, 0, stream>>>(coords, hash_table, offset_table,
                                           m0, m1, out, n);
}